// Round 14
// baseline (215.002 us; speedup 1.0000x reference)
//
#include <hip/hip_runtime.h>
#include <stdint.h>
#include <math.h>

#define B_ 4
#define S_ 2048
#define E_ 1024
#define H_ 16
#define D_ 64
#define M_ (B_*S_)

typedef __attribute__((ext_vector_type(8))) short bf16x8;
typedef __attribute__((ext_vector_type(4))) float f32x4;

__device__ __forceinline__ unsigned short f2bf(float f) {
  union { float f; uint32_t u; } v; v.f = f;
  uint32_t u = v.u;
  return (unsigned short)((u + 0x7FFFu + ((u >> 16) & 1u)) >> 16);
}

__device__ __forceinline__ void gload16(const void* g, void* l) {
  __builtin_amdgcn_global_load_lds(
      (__attribute__((address_space(1))) void*)g,
      (__attribute__((address_space(3))) void*)l, 16, 0, 0);
}

__device__ __forceinline__ uint32_t cvtpk(float lo, float hi) {
  uint32_t r;
  asm("v_cvt_pk_bf16_f32 %0, %1, %2" : "=v"(r) : "v"(lo), "v"(hi));
  return r;
}

// ---------------- fused f32->bf16 conversions + mask table ----------------
#define N1 ((M_*E_)/4)
#define N2 ((3*E_*E_)/4)
#define N3 ((E_*E_)/4)
#define NM ((B_*S_)/4)
__global__ __launch_bounds__(256) void cvt_all(const float* __restrict__ x,
                                               const float* __restrict__ w1,
                                               const float* __restrict__ w2,
                                               const int* __restrict__ mask,
                                               unsigned short* __restrict__ dst,
                                               float* __restrict__ maskf) {
  int i = blockIdx.x * 256 + threadIdx.x;
  if (i < N1 + N2 + N3) {
    const float* src;
    int j;
    if (i < N1) { src = x; j = i; }
    else if (i < N1 + N2) { src = w1; j = i - N1; }
    else { src = w2; j = i - N1 - N2; }
    float4 v = reinterpret_cast<const float4*>(src)[j];
    ushort4 o;
    o.x = f2bf(v.x); o.y = f2bf(v.y); o.z = f2bf(v.z); o.w = f2bf(v.w);
    reinterpret_cast<ushort4*>(dst)[i] = o;
  } else if (i < N1 + N2 + N3 + NM) {
    int j = i - (N1 + N2 + N3);
    int4 m = reinterpret_cast<const int4*>(mask)[j];
    float4 o;
    o.x = m.x ? 0.0f : -2.0e9f;
    o.y = m.y ? 0.0f : -2.0e9f;
    o.z = m.z ? 0.0f : -2.0e9f;
    o.w = m.w ? 0.0f : -2.0e9f;
    reinterpret_cast<float4*>(maskf)[j] = o;
  }
}

// ===== GEMM1: qkv = x @ Win^T + b -> Q / K' / Vt'  (128x128, BK=64, swizzled LDS) =====
__global__ __launch_bounds__(256) void gemm_qkv128(
    const unsigned short* __restrict__ A,
    const unsigned short* __restrict__ W,
    const float* __restrict__ bias,
    unsigned short* __restrict__ Qg,
    unsigned short* __restrict__ Kg,
    unsigned short* __restrict__ Vtg)
{
  // As[128][64] | Bs[128][64] = 32768 B exactly; V epilogue overlays T[64][136]
  __shared__ __align__(16) unsigned short SMEM[16384];
  unsigned short* As = SMEM;
  unsigned short* Bs = SMEM + 8192;
  const int tid = threadIdx.x;
  const int lane = tid & 63;
  const int wave = tid >> 6;
  const int wm = (wave >> 1) * 64, wn = (wave & 1) * 64;
  const int l15 = lane & 15, lg = lane >> 4;

  const int orig = blockIdx.y * 24 + blockIdx.x;
  const int xcd = orig & 7;
  const int idx = orig >> 3;
  const int tn = (xcd * 3 + (idx % 3)) * 128;
  const int tm = (idx / 3) * 128;

  f32x4 zero4 = {0.f, 0.f, 0.f, 0.f};
  f32x4 acc[4][4];
  #pragma unroll
  for (int mi = 0; mi < 4; ++mi)
    #pragma unroll
    for (int ni = 0; ni < 4; ++ni) acc[mi][ni] = zero4;

  const int r0 = tid >> 3;
  const int cg = ((tid & 7) ^ (r0 & 7)) * 8;
  const unsigned short* Abase = A + (size_t)(tm + r0) * E_ + cg;
  const unsigned short* Bbase = W + (size_t)(tn + r0) * E_ + cg;
  unsigned short* lA = As + tid * 8;
  unsigned short* lB = Bs + tid * 8;

  int aoff[4], boff[4];
  #pragma unroll
  for (int i = 0; i < 4; ++i) {
    aoff[i] = (wm + i*16 + l15)*64 + ((lg ^ (l15 & 7)) * 8);
    boff[i] = (wn + i*16 + l15)*64 + ((lg ^ (l15 & 7)) * 8);
  }
  const int x4a = ((lg ^ 4 ^ (l15 & 7)) * 8) - ((lg ^ (l15 & 7)) * 8);

  for (int k0 = 0; k0 < E_; k0 += 64) {
    #pragma unroll
    for (int j = 0; j < 4; ++j)
      gload16(Abase + k0 + j*32*E_, lA + j*2048);
    #pragma unroll
    for (int j = 0; j < 4; ++j)
      gload16(Bbase + k0 + j*32*E_, lB + j*2048);
    __syncthreads();
    #pragma unroll
    for (int kc = 0; kc < 2; ++kc) {
      bf16x8 af[4], bfv[4];
      #pragma unroll
      for (int mi = 0; mi < 4; ++mi)
        af[mi] = *(const bf16x8*)&As[aoff[mi] + kc*x4a];
      #pragma unroll
      for (int ni = 0; ni < 4; ++ni)
        bfv[ni] = *(const bf16x8*)&Bs[boff[ni] + kc*x4a];
      #pragma unroll
      for (int mi = 0; mi < 4; ++mi)
        #pragma unroll
        for (int ni = 0; ni < 4; ++ni)
          acc[mi][ni] = __builtin_amdgcn_mfma_f32_16x16x32_bf16(af[mi], bfv[ni], acc[mi][ni], 0, 0, 0);
    }
    __syncthreads();
  }

  const int sec = tn >> 10;
  if (sec < 2) {
    #pragma unroll
    for (int ni = 0; ni < 4; ++ni) {
      const int col = tn + wn + ni*16 + l15;
      const float bcol = bias[col];
      const int f2 = col & 1023;
      const int h = f2 >> 6, d = f2 & 63;
      #pragma unroll
      for (int mi = 0; mi < 4; ++mi) {
        #pragma unroll
        for (int r = 0; r < 4; ++r) {
          const int row = tm + wm + mi*16 + lg*4 + r;
          const int b = row >> 11, s = row & (S_-1);
          const size_t bh = (size_t)(b * H_ + h);
          float val = acc[mi][ni][r] + bcol;
          if (sec == 0) {
            Qg[(bh*S_ + s)*D_ + d] = f2bf(val * 0.18033688f);
          } else {
            const int ch = (d >> 3) ^ (s & 7);
            Kg[(bh*S_ + s)*D_ + ch*8 + (d & 7)] = f2bf(val);
          }
        }
      }
    }
  } else {
    // V epilogue: two 64-col passes through T[64][136] (fits in 32KB SMEM)
    unsigned short* T = SMEM;
    const int b = tm >> 11;
    const int sbase = (tm & (S_-1));
    #pragma unroll
    for (int p = 0; p < 2; ++p) {
      __syncthreads();
      if ((wave & 1) == p) {
        #pragma unroll
        for (int ni = 0; ni < 4; ++ni) {
          const int fq = ni*16 + l15;
          const float bcol = bias[tn + p*64 + fq];
          #pragma unroll
          for (int mi = 0; mi < 4; ++mi) {
            const int s0 = wm + mi*16 + lg*4;
            uint2 pv;
            pv.x = cvtpk(acc[mi][ni][0] + bcol, acc[mi][ni][1] + bcol);
            pv.y = cvtpk(acc[mi][ni][2] + bcol, acc[mi][ni][3] + bcol);
            *reinterpret_cast<uint2*>(&T[fq*136 + s0]) = pv;
          }
        }
      }
      __syncthreads();
      {
        const int fq = tid >> 2, sq = tid & 3;
        const int d = fq;
        const int h = ((tn & 1023) >> 6) + p;
        const size_t bh = (size_t)(b * H_ + h);
        unsigned short* vout = Vtg + (bh*D_ + d)*S_ + sbase + (sq >> 1)*64;
        const unsigned short* tin = &T[fq*136 + sq*32];
        #pragma unroll
        for (int j = 0; j < 4; ++j) {
          uint4 v = *reinterpret_cast<const uint4*>(&tin[j*8]);
          const int o = (sq & 1)*4 + j;
          *reinterpret_cast<uint4*>(&vout[(o ^ (d & 7))*8]) = v;
        }
      }
    }
  }
}

// --- Flash attention: 256 q/block, 8 waves x 32 q-rows, 128-key epochs,
//     subtile-ahead mask prefetch ---
__global__ __launch_bounds__(512, 4) void attn_fwd(
    const unsigned short* __restrict__ Qg,
    const unsigned short* __restrict__ Kg,
    const unsigned short* __restrict__ Vtg,
    const float* __restrict__ maskf,
    unsigned short* __restrict__ ctx)   // [B,S,E] bf16
{
  __shared__ __align__(16) unsigned char SMEM[65536];
  unsigned short* KsP = (unsigned short*)SMEM;            // [2][8192]
  unsigned short* VsP = (unsigned short*)(SMEM + 32768);  // [2][8192]
  const int tid = threadIdx.x, lane = tid & 63, wave = tid >> 6;
  const int l15 = lane & 15, lg = lane >> 4;

  const int lin = blockIdx.x;
  const int bh = (lin & 7) * 8 + (lin >> 6);
  const int qi = (lin >> 3) & 7;
  const int b = bh >> 4, h = bh & 15;
  const int q0 = qi * 256 + wave * 32;

  const unsigned short* Qb = Qg + (size_t)bh * S_ * D_;
  const unsigned short* Kb = Kg + (size_t)bh * S_ * D_;
  const unsigned short* Vb = Vtg + (size_t)bh * D_ * S_;
  const float* mrow = maskf + b * S_;

  bf16x8 qf[2][2];
  #pragma unroll
  for (int mi = 0; mi < 2; ++mi)
    #pragma unroll
    for (int kc = 0; kc < 2; ++kc)
      qf[mi][kc] = *(const bf16x8*)&Qb[(size_t)(q0 + mi*16 + l15)*D_ + kc*32 + lg*8];

  f32x4 zero4 = {0.f, 0.f, 0.f, 0.f};
  f32x4 accO[2][4];
  f32x4 accL[2] = {zero4, zero4};
  #pragma unroll
  for (int mi = 0; mi < 2; ++mi)
    #pragma unroll
    for (int df = 0; df < 4; ++df) accO[mi][df] = zero4;

  union { uint32_t u[4]; bf16x8 v; } ou;
  ou.u[0] = ou.u[1] = ou.u[2] = ou.u[3] = 0x3F803F80u;
  const bf16x8 onesv = ou.v;

  int kboff0[4], kboff1[4], vboff0[4], vboff1[4];
  #pragma unroll
  for (int kt = 0; kt < 4; ++kt) {
    const int krow = kt*16 + l15;
    kboff0[kt] = (krow*64 + ((lg ^ (krow & 7))*8)) * 2;
    kboff1[kt] = (krow*64 + (((4+lg) ^ (krow & 7))*8)) * 2;
  }
  #pragma unroll
  for (int df = 0; df < 4; ++df) {
    const int vrow = df*16 + l15;
    vboff0[df] = (vrow*64 + ((lg ^ (vrow & 7))*8)) * 2;
    vboff1[df] = (vrow*64 + (((4+lg) ^ (vrow & 7))*8)) * 2;
  }
  const char* KsB = (const char*)KsP;
  const char* VsB = (const char*)VsP;

  const int sr0 = tid >> 3, sc0 = (tid & 7) * 8;   // sr0 in 0..63

  // prologue: stage epoch 0 (128 keys); preload subtile-0 mask
  gload16(Kb + (size_t)sr0 * D_ + sc0,        KsP + tid*8);
  gload16(Kb + (size_t)(sr0 + 64) * D_ + sc0, KsP + (tid+512)*8);
  gload16(Vb + (size_t)sr0 * S_ + sc0,        VsP + tid*8);
  gload16(Vb + (size_t)sr0 * S_ + 64 + sc0,   VsP + (tid+512)*8);
  const unsigned short* kpre = Kb + (size_t)(128 + sr0) * D_ + sc0;
  const unsigned short* vpre = Vb + (size_t)sr0 * S_ + 128 + sc0;
  f32x4 mvA[4], mvB[4];
  #pragma unroll
  for (int kt = 0; kt < 4; ++kt)
    mvA[kt] = *(const f32x4*)&mrow[kt*16 + lg*4];
  const float* mnxt = mrow + 64 + lg*4;   // next subtile's mask
  __syncthreads();

#define SUBTILE(KT, VT, MVC, MVN, DO_MPF)                                       \
  {                                                                             \
    if (DO_MPF) {                                                               \
      _Pragma("unroll")                                                         \
      for (int kt = 0; kt < 4; ++kt)                                            \
        MVN[kt] = *(const f32x4*)&mnxt[kt*16];                                  \
      mnxt += 64;                                                               \
    }                                                                           \
    f32x4 s_[2][4];                                                             \
    __builtin_amdgcn_s_setprio(1);                                              \
    _Pragma("unroll")                                                           \
    for (int kt = 0; kt < 4; ++kt) {                                            \
      bf16x8 kf0 = *(const bf16x8*)((KT) + kboff0[kt]);                         \
      bf16x8 kf1 = *(const bf16x8*)((KT) + kboff1[kt]);                         \
      s_[0][kt] = __builtin_amdgcn_mfma_f32_16x16x32_bf16(kf0, qf[0][0], MVC[kt], 0, 0, 0); \
      s_[0][kt] = __builtin_amdgcn_mfma_f32_16x16x32_bf16(kf1, qf[0][1], s_[0][kt], 0, 0, 0); \
      s_[1][kt] = __builtin_amdgcn_mfma_f32_16x16x32_bf16(kf0, qf[1][0], MVC[kt], 0, 0, 0); \
      s_[1][kt] = __builtin_amdgcn_mfma_f32_16x16x32_bf16(kf1, qf[1][1], s_[1][kt], 0, 0, 0); \
    }                                                                           \
    __builtin_amdgcn_s_setprio(0);                                              \
    _Pragma("unroll")                                                           \
    for (int mi = 0; mi < 2; ++mi)                                              \
      _Pragma("unroll")                                                         \
      for (int kt = 0; kt < 4; ++kt)                                            \
        _Pragma("unroll")                                                       \
        for (int r = 0; r < 4; ++r)                                             \
          s_[mi][kt][r] = __builtin_amdgcn_exp2f(s_[mi][kt][r]);                \
    bf16x8 pa[2][2];                                                            \
    _Pragma("unroll")                                                           \
    for (int mi = 0; mi < 2; ++mi) {                                            \
      _Pragma("unroll")                                                         \
      for (int kk = 0; kk < 2; ++kk) {                                          \
        uint32_t a0 = cvtpk(s_[mi][2*kk][0],   s_[mi][2*kk][1]);                \
        uint32_t c1 = cvtpk(s_[mi][2*kk][2],   s_[mi][2*kk][3]);                \
        uint32_t b0 = cvtpk(s_[mi][2*kk+1][0], s_[mi][2*kk+1][1]);              \
        uint32_t d1 = cvtpk(s_[mi][2*kk+1][2], s_[mi][2*kk+1][3]);              \
        asm("v_permlane32_swap_b32 %0, %1" : "+v"(a0), "+v"(b0));               \
        asm("v_permlane16_swap_b32 %0, %1" : "+v"(a0), "+v"(b0));               \
        asm("v_permlane32_swap_b32 %0, %1" : "+v"(c1), "+v"(d1));               \
        asm("v_permlane16_swap_b32 %0, %1" : "+v"(c1), "+v"(d1));               \
        union { bf16x8 v; uint32_t u[4]; } w;                                   \
        w.u[0] = a0; w.u[1] = c1; w.u[2] = b0; w.u[3] = d1;                     \
        pa[mi][kk] = w.v;                                                       \
      }                                                                         \
    }                                                                           \
    __builtin_amdgcn_s_setprio(1);                                              \
    accL[0] = __builtin_amdgcn_mfma_f32_16x16x32_bf16(pa[0][0], onesv, accL[0], 0, 0, 0); \
    accL[1] = __builtin_amdgcn_mfma_f32_16x16x32_bf16(pa[1][0], onesv, accL[1], 0, 0, 0); \
    _Pragma("unroll")                                                           \
    for (int df = 0; df < 4; ++df) {                                            \
      bf16x8 vf = *(const bf16x8*)((VT) + vboff0[df]);                          \
      accO[0][df] = __builtin_amdgcn_mfma_f32_16x16x32_bf16(pa[0][0], vf, accO[0][df], 0, 0, 0); \
      accO[1][df] = __builtin_amdgcn_mfma_f32_16x16x32_bf16(pa[1][0], vf, accO[1][df], 0, 0, 0); \
    }                                                                           \
    accL[0] = __builtin_amdgcn_mfma_f32_16x16x32_bf16(pa[0][1], onesv, accL[0], 0, 0, 0); \
    accL[1] = __builtin_amdgcn_mfma_f32_16x16x32_bf16(pa[1][1], onesv, accL[1], 0, 0, 0); \
    _Pragma("unroll")                                                           \
    for (int df = 0; df < 4; ++df) {                                            \
      bf16x8 vf = *(const bf16x8*)((VT) + vboff1[df]);                          \
      accO[0][df] = __builtin_amdgcn_mfma_f32_16x16x32_bf16(pa[0][1], vf, accO[0][df], 0, 0, 0); \
      accO[1][df] = __builtin_amdgcn_mfma_f32_16x16x32_bf16(pa[1][1], vf, accO[1][df], 0, 0, 0); \
    }                                                                           \
    __builtin_amdgcn_s_setprio(0);                                              \
  }

#define EPOCH(CUR, DO_PF, LAST)                                                 \
  {                                                                             \
    if (DO_PF) {                                                                \
      gload16(kpre,           KsP + ((CUR)^1)*8192 + tid*8);                    \
      gload16(kpre + 64*D_,   KsP + ((CUR)^1)*8192 + (tid+512)*8);              \
      gload16(vpre,           VsP + ((CUR)^1)*8192 + tid*8);                    \
      gload16(vpre + 64,      VsP + ((CUR)^1)*8192 + (tid+512)*8);              \
      kpre += 128*D_; vpre += 128;                                              \
    }                                                                           \
    SUBTILE(KsB + (CUR)*16384,        VsB + (CUR)*16384,        mvA, mvB, 1)    \
    SUBTILE(KsB + (CUR)*16384 + 8192, VsB + (CUR)*16384 + 8192, mvB, mvA, !(LAST)) \
    __syncthreads();                                                            \
  }

  for (int ee = 0; ee < 16; ee += 2) {
    EPOCH(0, 1, 0)
    EPOCH(1, (ee < 14), (ee == 14))
  }
#undef EPOCH
#undef SUBTILE

  // ---- epilogue: normalize into per-wave LDS tile (stride 72 u16), then
  //      read back row-major so each 4-lane group writes a full 64B line ----
  unsigned short* T = (unsigned short*)SMEM + wave * 2304;   // 4608 B per wave
  #pragma unroll
  for (int mi = 0; mi < 2; ++mi) {
    #pragma unroll
    for (int r = 0; r < 4; ++r) {
      const float iv = 1.0f / accL[mi][r];
      const int q = mi*16 + lg*4 + r;
      #pragma unroll
      for (int df = 0; df < 4; ++df)
        T[q*72 + df*16 + l15] = f2bf(accO[mi][df][r] * iv);
    }
  }
  __syncthreads();
  {
    const int g = lane >> 2, c4 = lane & 3;
    #pragma unroll
    for (int j2 = 0; j2 < 4; ++j2) {
      const int t = j2*16 + g;             // 0..63 = (row, half-line)
      const int q = t >> 1, half = t & 1;
      uint4 v = *reinterpret_cast<const uint4*>(&T[q*72 + half*32 + c4*8]);
      const int srow = q0 + q;
      *reinterpret_cast<uint4*>(&ctx[((size_t)b*S_ + srow)*E_ + h*D_ + half*32 + c4*8]) = v;
    }
  }
}

// ------- GEMM2: out = x + ctx @ Wout^T + b   (128x128, BK=64, swizzled LDS) -------
__global__ __launch_bounds__(256) void gemm_out(
    const unsigned short* __restrict__ A,   // ctx [M_][E_]
    const unsigned short* __restrict__ W,   // w2b [E_][E_]
    const float* __restrict__ bias,
    const float* __restrict__ xres,
    float* __restrict__ out)
{
  __shared__ __align__(16) unsigned short As[128*64];
  __shared__ __align__(16) unsigned short Bs[128*64];
  const int tid = threadIdx.x;
  const int lane = tid & 63;
  const int wave = tid >> 6;
  const int wm = (wave >> 1) * 64, wn = (wave & 1) * 64;
  const int tm = blockIdx.y * 128, tn = blockIdx.x * 128;
  const int l15 = lane & 15, lg = lane >> 4;

  f32x4 zero4 = {0.f, 0.f, 0.f, 0.f};
  f32x4 acc[4][4];
  #pragma unroll
  for (int mi = 0; mi < 4; ++mi)
    #pragma unroll
    for (int ni = 0; ni < 4; ++ni) acc[mi][ni] = zero4;

  const int r0 = tid >> 3;
  const int cg = ((tid & 7) ^ (r0 & 7)) * 8;
  const unsigned short* Abase = A + (size_t)(tm + r0) * E_ + cg;
  const unsigned short* Bbase = W + (size_t)(tn + r0) * E_ + cg;
  unsigned short* lA = As + tid * 8;
  unsigned short* lB = Bs + tid * 8;

  int aoff[4], boff[4];
  #pragma unroll
  for (int i = 0; i < 4; ++i) {
    aoff[i] = (wm + i*16 + l15)*64 + ((lg ^ (l15 & 7)) * 8);
    boff[i] = (wn + i*16 + l15)*64 + ((lg ^ (l15 & 7)) * 8);
  }
  const int x4a = ((lg ^ 4 ^ (l15 & 7)) * 8) - ((lg ^ (l15 & 7)) * 8);

  for (int k0 = 0; k0 < E_; k0 += 64) {
    #pragma unroll
    for (int j = 0; j < 4; ++j)
      gload16(Abase + k0 + j*32*E_, lA + j*2048);
    #pragma unroll
    for (int j = 0; j < 4; ++j)
      gload16(Bbase + k0 + j*32*E_, lB + j*2048);
    __syncthreads();
    #pragma unroll
    for (int kc = 0; kc < 2; ++kc) {
      bf16x8 af[4], bfv[4];
      #pragma unroll
      for (int mi = 0; mi < 4; ++mi)
        af[mi] = *(const bf16x8*)&As[aoff[mi] + kc*x4a];
      #pragma unroll
      for (int ni = 0; ni < 4; ++ni)
        bfv[ni] = *(const bf16x8*)&Bs[boff[ni] + kc*x4a];
      #pragma unroll
      for (int mi = 0; mi < 4; ++mi)
        #pragma unroll
        for (int ni = 0; ni < 4; ++ni)
          acc[mi][ni] = __builtin_amdgcn_mfma_f32_16x16x32_bf16(af[mi], bfv[ni], acc[mi][ni], 0, 0, 0);
    }
    __syncthreads();
  }

  #pragma unroll
  for (int ni = 0; ni < 4; ++ni) {
    const int col = tn + wn + ni*16 + l15;
    const float bcol = bias[col];
    #pragma unroll
    for (int mi = 0; mi < 4; ++mi) {
      #pragma unroll
      for (int r = 0; r < 4; ++r) {
        const int row = tm + wm + mi*16 + lg*4 + r;
        out[(size_t)row*E_ + col] = xres[(size_t)row*E_ + col] + acc[mi][ni][r] + bcol;
      }
    }
  }
}

extern "C" void kernel_launch(void* const* d_in, const int* in_sizes, int n_in,
                              void* d_out, int out_size, void* d_ws, size_t ws_size,
                              hipStream_t stream) {
  const float* x  = (const float*)d_in[0];
  const float* w1 = (const float*)d_in[1];
  const float* b1 = (const float*)d_in[2];
  const float* w2 = (const float*)d_in[3];
  const float* b2 = (const float*)d_in[4];
  const int* mask = (const int*)d_in[5];
  float* out = (float*)d_out;

  const size_t SZ = (size_t)B_*H_*S_*D_;
  unsigned short* Qg  = (unsigned short*)d_ws;
  unsigned short* Kg  = Qg + SZ;
  unsigned short* Vtg = Kg + SZ;
  unsigned short* xb  = Vtg + SZ;              // reused as ctx after attention
  unsigned short* w1b = xb + (size_t)M_*E_;
  unsigned short* w2b = w1b + (size_t)3*E_*E_;
  float* maskf = (float*)(w2b + (size_t)E_*E_);
  unsigned short* ctx = xb;

  const int ntot = N1 + N2 + N3 + NM;
  cvt_all<<<(ntot + 255)/256, 256, 0, stream>>>(x, w1, w2, mask, xb, maskf);

  gemm_qkv128<<<dim3(24, 64), 256, 0, stream>>>(xb, w1b, b1, Qg, Kg, Vtg);
  attn_fwd<<<512, 512, 0, stream>>>(Qg, Kg, Vtg, maskf, ctx);
  gemm_out<<<dim3(E_/128, M_/128), 256, 0, stream>>>(ctx, w2b, b2, x, out);
}

// Round 15
// 189.642 us; speedup vs baseline: 1.1337x; 1.1337x over previous
//
#include <hip/hip_runtime.h>
#include <stdint.h>
#include <math.h>

#define B_ 4
#define S_ 2048
#define E_ 1024
#define H_ 16
#define D_ 64
#define M_ (B_*S_)

typedef __attribute__((ext_vector_type(8))) short bf16x8;
typedef __attribute__((ext_vector_type(4))) float f32x4;

__device__ __forceinline__ unsigned short f2bf(float f) {
  union { float f; uint32_t u; } v; v.f = f;
  uint32_t u = v.u;
  return (unsigned short)((u + 0x7FFFu + ((u >> 16) & 1u)) >> 16);
}

__device__ __forceinline__ void gload16(const void* g, void* l) {
  __builtin_amdgcn_global_load_lds(
      (__attribute__((address_space(1))) void*)g,
      (__attribute__((address_space(3))) void*)l, 16, 0, 0);
}

__device__ __forceinline__ uint32_t cvtpk(float lo, float hi) {
  uint32_t r;
  asm("v_cvt_pk_bf16_f32 %0, %1, %2" : "=v"(r) : "v"(lo), "v"(hi));
  return r;
}

// ---------------- fused f32->bf16 conversions + mask table ----------------
#define N1 ((M_*E_)/4)
#define N2 ((3*E_*E_)/4)
#define N3 ((E_*E_)/4)
#define NM ((B_*S_)/4)
__global__ __launch_bounds__(256) void cvt_all(const float* __restrict__ x,
                                               const float* __restrict__ w1,
                                               const float* __restrict__ w2,
                                               const int* __restrict__ mask,
                                               unsigned short* __restrict__ dst,
                                               float* __restrict__ maskf) {
  int i = blockIdx.x * 256 + threadIdx.x;
  if (i < N1 + N2 + N3) {
    const float* src;
    int j;
    if (i < N1) { src = x; j = i; }
    else if (i < N1 + N2) { src = w1; j = i - N1; }
    else { src = w2; j = i - N1 - N2; }
    float4 v = reinterpret_cast<const float4*>(src)[j];
    ushort4 o;
    o.x = f2bf(v.x); o.y = f2bf(v.y); o.z = f2bf(v.z); o.w = f2bf(v.w);
    reinterpret_cast<ushort4*>(dst)[i] = o;
  } else if (i < N1 + N2 + N3 + NM) {
    int j = i - (N1 + N2 + N3);
    int4 m = reinterpret_cast<const int4*>(mask)[j];
    float4 o;
    o.x = m.x ? 0.0f : -2.0e9f;
    o.y = m.y ? 0.0f : -2.0e9f;
    o.z = m.z ? 0.0f : -2.0e9f;
    o.w = m.w ? 0.0f : -2.0e9f;
    reinterpret_cast<float4*>(maskf)[j] = o;
  }
}

// ===== GEMM1: qkv = x @ Win^T + b -> Q / K' / Vt'  (128x128, BK=64, swizzled LDS,
//       32KB SMEM -> 5 blocks/CU) =====
__global__ __launch_bounds__(256) void gemm_qkv128(
    const unsigned short* __restrict__ A,
    const unsigned short* __restrict__ W,
    const float* __restrict__ bias,
    unsigned short* __restrict__ Qg,
    unsigned short* __restrict__ Kg,
    unsigned short* __restrict__ Vtg)
{
  // As[128][64] | Bs[128][64] = 32768 B exactly; V epilogue overlays T[64][136]
  __shared__ __align__(16) unsigned short SMEM[16384];
  unsigned short* As = SMEM;
  unsigned short* Bs = SMEM + 8192;
  const int tid = threadIdx.x;
  const int lane = tid & 63;
  const int wave = tid >> 6;
  const int wm = (wave >> 1) * 64, wn = (wave & 1) * 64;
  const int l15 = lane & 15, lg = lane >> 4;

  const int orig = blockIdx.y * 24 + blockIdx.x;
  const int xcd = orig & 7;
  const int idx = orig >> 3;
  const int tn = (xcd * 3 + (idx % 3)) * 128;
  const int tm = (idx / 3) * 128;

  f32x4 zero4 = {0.f, 0.f, 0.f, 0.f};
  f32x4 acc[4][4];
  #pragma unroll
  for (int mi = 0; mi < 4; ++mi)
    #pragma unroll
    for (int ni = 0; ni < 4; ++ni) acc[mi][ni] = zero4;

  const int r0 = tid >> 3;
  const int cg = ((tid & 7) ^ (r0 & 7)) * 8;
  const unsigned short* Abase = A + (size_t)(tm + r0) * E_ + cg;
  const unsigned short* Bbase = W + (size_t)(tn + r0) * E_ + cg;
  unsigned short* lA = As + tid * 8;
  unsigned short* lB = Bs + tid * 8;

  int aoff[4], boff[4];
  #pragma unroll
  for (int i = 0; i < 4; ++i) {
    aoff[i] = (wm + i*16 + l15)*64 + ((lg ^ (l15 & 7)) * 8);
    boff[i] = (wn + i*16 + l15)*64 + ((lg ^ (l15 & 7)) * 8);
  }
  const int x4a = ((lg ^ 4 ^ (l15 & 7)) * 8) - ((lg ^ (l15 & 7)) * 8);

  for (int k0 = 0; k0 < E_; k0 += 64) {
    #pragma unroll
    for (int j = 0; j < 4; ++j)
      gload16(Abase + k0 + j*32*E_, lA + j*2048);
    #pragma unroll
    for (int j = 0; j < 4; ++j)
      gload16(Bbase + k0 + j*32*E_, lB + j*2048);
    __syncthreads();
    #pragma unroll
    for (int kc = 0; kc < 2; ++kc) {
      bf16x8 af[4], bfv[4];
      #pragma unroll
      for (int mi = 0; mi < 4; ++mi)
        af[mi] = *(const bf16x8*)&As[aoff[mi] + kc*x4a];
      #pragma unroll
      for (int ni = 0; ni < 4; ++ni)
        bfv[ni] = *(const bf16x8*)&Bs[boff[ni] + kc*x4a];
      #pragma unroll
      for (int mi = 0; mi < 4; ++mi)
        #pragma unroll
        for (int ni = 0; ni < 4; ++ni)
          acc[mi][ni] = __builtin_amdgcn_mfma_f32_16x16x32_bf16(af[mi], bfv[ni], acc[mi][ni], 0, 0, 0);
    }
    __syncthreads();
  }

  const int sec = tn >> 10;
  if (sec < 2) {
    #pragma unroll
    for (int ni = 0; ni < 4; ++ni) {
      const int col = tn + wn + ni*16 + l15;
      const float bcol = bias[col];
      const int f2 = col & 1023;
      const int h = f2 >> 6, d = f2 & 63;
      #pragma unroll
      for (int mi = 0; mi < 4; ++mi) {
        #pragma unroll
        for (int r = 0; r < 4; ++r) {
          const int row = tm + wm + mi*16 + lg*4 + r;
          const int b = row >> 11, s = row & (S_-1);
          const size_t bh = (size_t)(b * H_ + h);
          float val = acc[mi][ni][r] + bcol;
          if (sec == 0) {
            Qg[(bh*S_ + s)*D_ + d] = f2bf(val * 0.18033688f);
          } else {
            const int ch = (d >> 3) ^ (s & 7);
            Kg[(bh*S_ + s)*D_ + ch*8 + (d & 7)] = f2bf(val);
          }
        }
      }
    }
  } else {
    // V epilogue: two 64-col passes through T[64][136] (fits in 32KB SMEM)
    unsigned short* T = SMEM;
    const int b = tm >> 11;
    const int sbase = (tm & (S_-1));
    #pragma unroll
    for (int p = 0; p < 2; ++p) {
      __syncthreads();
      if ((wave & 1) == p) {
        #pragma unroll
        for (int ni = 0; ni < 4; ++ni) {
          const int fq = ni*16 + l15;
          const float bcol = bias[tn + p*64 + fq];
          #pragma unroll
          for (int mi = 0; mi < 4; ++mi) {
            const int s0 = wm + mi*16 + lg*4;
            uint2 pv;
            pv.x = cvtpk(acc[mi][ni][0] + bcol, acc[mi][ni][1] + bcol);
            pv.y = cvtpk(acc[mi][ni][2] + bcol, acc[mi][ni][3] + bcol);
            *reinterpret_cast<uint2*>(&T[fq*136 + s0]) = pv;
          }
        }
      }
      __syncthreads();
      {
        const int fq = tid >> 2, sq = tid & 3;
        const int d = fq;
        const int h = ((tn & 1023) >> 6) + p;
        const size_t bh = (size_t)(b * H_ + h);
        unsigned short* vout = Vtg + (bh*D_ + d)*S_ + sbase + (sq >> 1)*64;
        const unsigned short* tin = &T[fq*136 + sq*32];
        #pragma unroll
        for (int j = 0; j < 4; ++j) {
          uint4 v = *reinterpret_cast<const uint4*>(&tin[j*8]);
          const int o = (sq & 1)*4 + j;
          *reinterpret_cast<uint4*>(&vout[(o ^ (d & 7))*8]) = v;
        }
      }
    }
  }
}

// --- Flash attention: 256 q/block, 8 waves x 32 q-rows, 128-key epochs ---
__global__ __launch_bounds__(512, 4) void attn_fwd(
    const unsigned short* __restrict__ Qg,
    const unsigned short* __restrict__ Kg,
    const unsigned short* __restrict__ Vtg,
    const float* __restrict__ maskf,
    unsigned short* __restrict__ ctx)   // [B,S,E] bf16
{
  // K/V double buffers: 2 x 16KB each (128 keys/epoch). Epilogue overlays T tiles.
  __shared__ __align__(16) unsigned char SMEM[65536];
  unsigned short* KsP = (unsigned short*)SMEM;            // [2][8192]
  unsigned short* VsP = (unsigned short*)(SMEM + 32768);  // [2][8192]
  const int tid = threadIdx.x, lane = tid & 63, wave = tid >> 6;
  const int l15 = lane & 15, lg = lane >> 4;

  // XCD head-grouping: each XCD owns 8 whole heads.
  const int lin = blockIdx.x;
  const int bh = (lin & 7) * 8 + (lin >> 6);
  const int qi = (lin >> 3) & 7;
  const int b = bh >> 4, h = bh & 15;
  const int q0 = qi * 256 + wave * 32;

  const unsigned short* Qb = Qg + (size_t)bh * S_ * D_;
  const unsigned short* Kb = Kg + (size_t)bh * S_ * D_;
  const unsigned short* Vb = Vtg + (size_t)bh * D_ * S_;
  const float* mrow = maskf + b * S_;

  bf16x8 qf[2][2];
  #pragma unroll
  for (int mi = 0; mi < 2; ++mi)
    #pragma unroll
    for (int kc = 0; kc < 2; ++kc)
      qf[mi][kc] = *(const bf16x8*)&Qb[(size_t)(q0 + mi*16 + l15)*D_ + kc*32 + lg*8];

  f32x4 zero4 = {0.f, 0.f, 0.f, 0.f};
  f32x4 accO[2][4];
  f32x4 accL[2] = {zero4, zero4};
  #pragma unroll
  for (int mi = 0; mi < 2; ++mi)
    #pragma unroll
    for (int df = 0; df < 4; ++df) accO[mi][df] = zero4;

  union { uint32_t u[4]; bf16x8 v; } ou;
  ou.u[0] = ou.u[1] = ou.u[2] = ou.u[3] = 0x3F803F80u;
  const bf16x8 onesv = ou.v;

  // hoisted swizzled LDS byte offsets (per 64-row sub-tile)
  int kboff0[4], kboff1[4], vboff0[4], vboff1[4];
  #pragma unroll
  for (int kt = 0; kt < 4; ++kt) {
    const int krow = kt*16 + l15;
    kboff0[kt] = (krow*64 + ((lg ^ (krow & 7))*8)) * 2;
    kboff1[kt] = (krow*64 + (((4+lg) ^ (krow & 7))*8)) * 2;
  }
  #pragma unroll
  for (int df = 0; df < 4; ++df) {
    const int vrow = df*16 + l15;
    vboff0[df] = (vrow*64 + ((lg ^ (vrow & 7))*8)) * 2;
    vboff1[df] = (vrow*64 + (((4+lg) ^ (vrow & 7))*8)) * 2;
  }
  const char* KsB = (const char*)KsP;
  const char* VsB = (const char*)VsP;

  const int sr0 = tid >> 3, sc0 = (tid & 7) * 8;   // sr0 in 0..63

  // prologue: stage epoch 0 (128 keys) into buffer 0
  gload16(Kb + (size_t)sr0 * D_ + sc0,        KsP + tid*8);
  gload16(Kb + (size_t)(sr0 + 64) * D_ + sc0, KsP + (tid+512)*8);
  gload16(Vb + (size_t)sr0 * S_ + sc0,        VsP + tid*8);
  gload16(Vb + (size_t)sr0 * S_ + 64 + sc0,   VsP + (tid+512)*8);
  const unsigned short* kpre = Kb + (size_t)(128 + sr0) * D_ + sc0;
  const unsigned short* vpre = Vb + (size_t)sr0 * S_ + 128 + sc0;
  const float* mcur = mrow + lg*4;
  __syncthreads();

#define SUBTILE(KT, VT, MOFF)                                                   \
  {                                                                             \
    f32x4 mv[4];                                                                \
    _Pragma("unroll")                                                           \
    for (int kt = 0; kt < 4; ++kt)                                              \
      mv[kt] = *(const f32x4*)&mcur[(MOFF) + kt*16];                            \
    f32x4 s_[2][4];                                                             \
    __builtin_amdgcn_s_setprio(1);                                              \
    _Pragma("unroll")                                                           \
    for (int kt = 0; kt < 4; ++kt) {                                            \
      bf16x8 kf0 = *(const bf16x8*)((KT) + kboff0[kt]);                         \
      bf16x8 kf1 = *(const bf16x8*)((KT) + kboff1[kt]);                         \
      s_[0][kt] = __builtin_amdgcn_mfma_f32_16x16x32_bf16(kf0, qf[0][0], mv[kt], 0, 0, 0); \
      s_[0][kt] = __builtin_amdgcn_mfma_f32_16x16x32_bf16(kf1, qf[0][1], s_[0][kt], 0, 0, 0); \
      s_[1][kt] = __builtin_amdgcn_mfma_f32_16x16x32_bf16(kf0, qf[1][0], mv[kt], 0, 0, 0); \
      s_[1][kt] = __builtin_amdgcn_mfma_f32_16x16x32_bf16(kf1, qf[1][1], s_[1][kt], 0, 0, 0); \
    }                                                                           \
    __builtin_amdgcn_s_setprio(0);                                              \
    _Pragma("unroll")                                                           \
    for (int mi = 0; mi < 2; ++mi)                                              \
      _Pragma("unroll")                                                         \
      for (int kt = 0; kt < 4; ++kt)                                            \
        _Pragma("unroll")                                                       \
        for (int r = 0; r < 4; ++r)                                             \
          s_[mi][kt][r] = __builtin_amdgcn_exp2f(s_[mi][kt][r]);                \
    bf16x8 pa[2][2];                                                            \
    _Pragma("unroll")                                                           \
    for (int mi = 0; mi < 2; ++mi) {                                            \
      _Pragma("unroll")                                                         \
      for (int kk = 0; kk < 2; ++kk) {                                          \
        uint32_t a0 = cvtpk(s_[mi][2*kk][0],   s_[mi][2*kk][1]);                \
        uint32_t c1 = cvtpk(s_[mi][2*kk][2],   s_[mi][2*kk][3]);                \
        uint32_t b0 = cvtpk(s_[mi][2*kk+1][0], s_[mi][2*kk+1][1]);              \
        uint32_t d1 = cvtpk(s_[mi][2*kk+1][2], s_[mi][2*kk+1][3]);              \
        asm("v_permlane32_swap_b32 %0, %1" : "+v"(a0), "+v"(b0));               \
        asm("v_permlane16_swap_b32 %0, %1" : "+v"(a0), "+v"(b0));               \
        asm("v_permlane32_swap_b32 %0, %1" : "+v"(c1), "+v"(d1));               \
        asm("v_permlane16_swap_b32 %0, %1" : "+v"(c1), "+v"(d1));               \
        union { bf16x8 v; uint32_t u[4]; } w;                                   \
        w.u[0] = a0; w.u[1] = c1; w.u[2] = b0; w.u[3] = d1;                     \
        pa[mi][kk] = w.v;                                                       \
      }                                                                         \
    }                                                                           \
    __builtin_amdgcn_s_setprio(1);                                              \
    accL[0] = __builtin_amdgcn_mfma_f32_16x16x32_bf16(pa[0][0], onesv, accL[0], 0, 0, 0); \
    accL[1] = __builtin_amdgcn_mfma_f32_16x16x32_bf16(pa[1][0], onesv, accL[1], 0, 0, 0); \
    _Pragma("unroll")                                                           \
    for (int df = 0; df < 4; ++df) {                                            \
      bf16x8 vf = *(const bf16x8*)((VT) + vboff0[df]);                          \
      accO[0][df] = __builtin_amdgcn_mfma_f32_16x16x32_bf16(pa[0][0], vf, accO[0][df], 0, 0, 0); \
      accO[1][df] = __builtin_amdgcn_mfma_f32_16x16x32_bf16(pa[1][0], vf, accO[1][df], 0, 0, 0); \
    }                                                                           \
    accL[0] = __builtin_amdgcn_mfma_f32_16x16x32_bf16(pa[0][1], onesv, accL[0], 0, 0, 0); \
    accL[1] = __builtin_amdgcn_mfma_f32_16x16x32_bf16(pa[1][1], onesv, accL[1], 0, 0, 0); \
    _Pragma("unroll")                                                           \
    for (int df = 0; df < 4; ++df) {                                            \
      bf16x8 vf = *(const bf16x8*)((VT) + vboff1[df]);                          \
      accO[0][df] = __builtin_amdgcn_mfma_f32_16x16x32_bf16(pa[0][1], vf, accO[0][df], 0, 0, 0); \
      accO[1][df] = __builtin_amdgcn_mfma_f32_16x16x32_bf16(pa[1][1], vf, accO[1][df], 0, 0, 0); \
    }                                                                           \
    __builtin_amdgcn_s_setprio(0);                                              \
  }

#define EPOCH(CUR, DO_PF)                                                       \
  {                                                                             \
    if (DO_PF) {                                                                \
      gload16(kpre,           KsP + ((CUR)^1)*8192 + tid*8);                    \
      gload16(kpre + 64*D_,   KsP + ((CUR)^1)*8192 + (tid+512)*8);              \
      gload16(vpre,           VsP + ((CUR)^1)*8192 + tid*8);                    \
      gload16(vpre + 64,      VsP + ((CUR)^1)*8192 + (tid+512)*8);              \
      kpre += 128*D_; vpre += 128;                                              \
    }                                                                           \
    SUBTILE(KsB + (CUR)*16384,        VsB + (CUR)*16384,        0)              \
    SUBTILE(KsB + (CUR)*16384 + 8192, VsB + (CUR)*16384 + 8192, 64)             \
    mcur += 128;                                                                \
    __syncthreads();                                                            \
  }

  for (int ee = 0; ee < 16; ee += 2) {
    EPOCH(0, 1)
    EPOCH(1, (ee < 14))
  }
#undef EPOCH
#undef SUBTILE

  // ---- epilogue: normalize into per-wave LDS tile (stride 72 u16), then
  //      read back row-major so each 4-lane group writes a full 64B line ----
  unsigned short* T = (unsigned short*)SMEM + wave * 2304;   // 4608 B per wave
  #pragma unroll
  for (int mi = 0; mi < 2; ++mi) {
    #pragma unroll
    for (int r = 0; r < 4; ++r) {
      const float iv = 1.0f / accL[mi][r];
      const int q = mi*16 + lg*4 + r;
      #pragma unroll
      for (int df = 0; df < 4; ++df)
        T[q*72 + df*16 + l15] = f2bf(accO[mi][df][r] * iv);
    }
  }
  __syncthreads();
  {
    const int g = lane >> 2, c4 = lane & 3;
    #pragma unroll
    for (int j2 = 0; j2 < 4; ++j2) {
      const int t = j2*16 + g;             // 0..63 = (row, half-line)
      const int q = t >> 1, half = t & 1;
      uint4 v = *reinterpret_cast<const uint4*>(&T[q*72 + half*32 + c4*8]);
      const int srow = q0 + q;
      *reinterpret_cast<uint4*>(&ctx[((size_t)b*S_ + srow)*E_ + h*D_ + half*32 + c4*8]) = v;
    }
  }
}

// ------- GEMM2: out = x + ctx @ Wout^T + b   (128x128, BK=64, swizzled LDS) -------
__global__ __launch_bounds__(256) void gemm_out(
    const unsigned short* __restrict__ A,   // ctx [M_][E_]
    const unsigned short* __restrict__ W,   // w2b [E_][E_]
    const float* __restrict__ bias,
    const float* __restrict__ xres,
    float* __restrict__ out)
{
  __shared__ __align__(16) unsigned short As[128*64];
  __shared__ __align__(16) unsigned short Bs[128*64];
  const int tid = threadIdx.x;
  const int lane = tid & 63;
  const int wave = tid >> 6;
  const int wm = (wave >> 1) * 64, wn = (wave & 1) * 64;
  const int tm = blockIdx.y * 128, tn = blockIdx.x * 128;
  const int l15 = lane & 15, lg = lane >> 4;

  f32x4 zero4 = {0.f, 0.f, 0.f, 0.f};
  f32x4 acc[4][4];
  #pragma unroll
  for (int mi = 0; mi < 4; ++mi)
    #pragma unroll
    for (int ni = 0; ni < 4; ++ni) acc[mi][ni] = zero4;

  const int r0 = tid >> 3;
  const int cg = ((tid & 7) ^ (r0 & 7)) * 8;
  const unsigned short* Abase = A + (size_t)(tm + r0) * E_ + cg;
  const unsigned short* Bbase = W + (size_t)(tn + r0) * E_ + cg;
  unsigned short* lA = As + tid * 8;
  unsigned short* lB = Bs + tid * 8;

  int aoff[4], boff[4];
  #pragma unroll
  for (int i = 0; i < 4; ++i) {
    aoff[i] = (wm + i*16 + l15)*64 + ((lg ^ (l15 & 7)) * 8);
    boff[i] = (wn + i*16 + l15)*64 + ((lg ^ (l15 & 7)) * 8);
  }
  const int x4a = ((lg ^ 4 ^ (l15 & 7)) * 8) - ((lg ^ (l15 & 7)) * 8);

  for (int k0 = 0; k0 < E_; k0 += 64) {
    #pragma unroll
    for (int j = 0; j < 4; ++j)
      gload16(Abase + k0 + j*32*E_, lA + j*2048);
    #pragma unroll
    for (int j = 0; j < 4; ++j)
      gload16(Bbase + k0 + j*32*E_, lB + j*2048);
    __syncthreads();
    #pragma unroll
    for (int kc = 0; kc < 2; ++kc) {
      bf16x8 af[4], bfv[4];
      #pragma unroll
      for (int mi = 0; mi < 4; ++mi)
        af[mi] = *(const bf16x8*)&As[aoff[mi] + kc*x4a];
      #pragma unroll
      for (int ni = 0; ni < 4; ++ni)
        bfv[ni] = *(const bf16x8*)&Bs[boff[ni] + kc*x4a];
      #pragma unroll
      for (int mi = 0; mi < 4; ++mi)
        #pragma unroll
        for (int ni = 0; ni < 4; ++ni)
          acc[mi][ni] = __builtin_amdgcn_mfma_f32_16x16x32_bf16(af[mi], bfv[ni], acc[mi][ni], 0, 0, 0);
    }
    __syncthreads();
  }

  #pragma unroll
  for (int ni = 0; ni < 4; ++ni) {
    const int col = tn + wn + ni*16 + l15;
    const float bcol = bias[col];
    #pragma unroll
    for (int mi = 0; mi < 4; ++mi) {
      #pragma unroll
      for (int r = 0; r < 4; ++r) {
        const int row = tm + wm + mi*16 + lg*4 + r;
        out[(size_t)row*E_ + col] = xres[(size_t)row*E_ + col] + acc[mi][ni][r] + bcol;
      }
    }
  }
}

extern "C" void kernel_launch(void* const* d_in, const int* in_sizes, int n_in,
                              void* d_out, int out_size, void* d_ws, size_t ws_size,
                              hipStream_t stream) {
  const float* x  = (const float*)d_in[0];
  const float* w1 = (const float*)d_in[1];
  const float* b1 = (const float*)d_in[2];
  const float* w2 = (const float*)d_in[3];
  const float* b2 = (const float*)d_in[4];
  const int* mask = (const int*)d_in[5];
  float* out = (float*)d_out;

  const size_t SZ = (size_t)B_*H_*S_*D_;
  unsigned short* Qg  = (unsigned short*)d_ws;
  unsigned short* Kg  = Qg + SZ;
  unsigned short* Vtg = Kg + SZ;
  unsigned short* xb  = Vtg + SZ;              // reused as ctx after attention
  unsigned short* w1b = xb + (size_t)M_*E_;
  unsigned short* w2b = w1b + (size_t)3*E_*E_;
  float* maskf = (float*)(w2b + (size_t)E_*E_);
  unsigned short* ctx = xb;

  const int ntot = N1 + N2 + N3 + NM;
  cvt_all<<<(ntot + 255)/256, 256, 0, stream>>>(x, w1, w2, mask, xb, maskf);

  gemm_qkv128<<<dim3(24, 64), 256, 0, stream>>>(xb, w1b, b1, Qg, Kg, Vtg);
  attn_fwd<<<512, 512, 0, stream>>>(Qg, Kg, Vtg, maskf, ctx);
  gemm_out<<<dim3(E_/128, M_/128), 256, 0, stream>>>(ctx, w2b, b2, x, out);
}